// Round 1
// baseline (470.315 us; speedup 1.0000x reference)
//
#include <hip/hip_runtime.h>
#include <cstdint>
#include <cstddef>

// ---------------------------------------------------------------------------
// EdgeDecoder: out[e] = sigmoid(W2ᵀ·elu(W1ᵀ·elu(W0ᵀ·[src_emb[s]; dst_emb[d]]+b0)+b1)+b2)
// Two decoders (ui, iu), E=1e6 edges each. f16 MFMA (16x16x32), weights staged
// in LDS in B-fragment order, embeddings pre-converted to f16 in d_ws.
// ---------------------------------------------------------------------------

#define E_EDGES   1000000
#define NTILES    31250        // E / 32 (exact)
#define LDS_HALFS 65536        // 128 KiB of _Float16
#define W1_BASE   32768        // half-index of W1 fragment region
#define TB_BASE   49152        // half-index of transpose buffers (8 waves x 2048)

typedef _Float16 half8 __attribute__((ext_vector_type(8)));
typedef _Float16 half4v __attribute__((ext_vector_type(4)));
typedef float    f32x4 __attribute__((ext_vector_type(4)));

// fp32 -> f16 table conversion (vectorized, one float4 per thread)
__global__ void cvt_f32_f16(const float* __restrict__ in, _Float16* __restrict__ out, int n4) {
    int i = blockIdx.x * blockDim.x + threadIdx.x;
    if (i < n4) {
        float4 f = ((const float4*)in)[i];
        half4v h;
        h[0] = (_Float16)f.x; h[1] = (_Float16)f.y;
        h[2] = (_Float16)f.z; h[3] = (_Float16)f.w;
        ((half4v*)out)[i] = h;
    }
}

template<bool PRE16>
__global__ __launch_bounds__(512, 2) void edge_mlp(
    const void* __restrict__ src_tab, const void* __restrict__ dst_tab,
    const int* __restrict__ src_idx, const int* __restrict__ dst_idx,
    const float* __restrict__ W0, const float* __restrict__ b0,
    const float* __restrict__ W1, const float* __restrict__ b1,
    const float* __restrict__ W2, const float* __restrict__ b2,
    float* __restrict__ out)
{
    __shared__ __align__(16) _Float16 lds[LDS_HALFS];
    const int tid = threadIdx.x;
    const int l = tid & 63;        // lane
    const int w = tid >> 6;        // wave 0..7
    const int n = l & 15;          // low lane bits: col index (B/C) or row (A)
    const int g = l >> 4;          // lane quad 0..3

    // ---- preload W0 into LDS in B-fragment order: frag f=kk*8+j, 64 frags ----
    // fragment element (lane l, elem i): k = kk*32 + (l>>4)*8 + i, col = j*16 + (l&15)
    #pragma unroll
    for (int q = 0; q < 8; ++q) {
        const int f = w * 8 + q;
        const int kk = f >> 3, j = f & 7;
        const int kbase = kk * 32 + g * 8;
        const int col = j * 16 + n;
        half8 fr;
        #pragma unroll
        for (int i = 0; i < 8; ++i) fr[i] = (_Float16)W0[(kbase + i) * 128 + col];
        *(half8*)&lds[f * 512 + l * 8] = fr;
    }
    // ---- preload W1 (32 frags) ----
    #pragma unroll
    for (int q = 0; q < 4; ++q) {
        const int f = w * 4 + q;
        const int kk = f >> 3, j = f & 7;
        const int kbase = kk * 32 + g * 8;
        const int col = j * 16 + n;
        half8 fr;
        #pragma unroll
        for (int i = 0; i < 8; ++i) fr[i] = (_Float16)W1[(kbase + i) * 128 + col];
        *(half8*)&lds[W1_BASE + f * 512 + l * 8] = fr;
    }

    // loop-invariant per-lane epilogue constants (col = j*16 + n)
    float b0r[8], b1r[8], w2r[8];
    #pragma unroll
    for (int j = 0; j < 8; ++j) {
        b0r[j] = b0[j * 16 + n];
        b1r[j] = b1[j * 16 + n];
        w2r[j] = W2[j * 16 + n];
    }
    const float b2s = b2[0];
    __syncthreads();

    _Float16* tbuf = &lds[TB_BASE + w * 2048];   // wave-private 16x128 f16
    const half8* w0f = (const half8*)&lds[0];
    const half8* w1f = (const half8*)&lds[W1_BASE];

    const int wave_gid = blockIdx.x * 8 + w;
    const int wave_stride = gridDim.x * 8;

    for (int t = wave_gid; t < NTILES; t += wave_stride) {
        const int e0 = t * 32;

        // ---- gather A fragments: 2 sets x 16 rows x 256 K ----
        half8 a0[2][8];
        #pragma unroll
        for (int s = 0; s < 2; ++s) {
            const int e = e0 + s * 16 + n;       // A-layout: m = lane&15
            const int si = src_idx[e];
            const int di = dst_idx[e];
            if (PRE16) {
                const _Float16* rs = (const _Float16*)src_tab + (size_t)si * 128;
                const _Float16* rd = (const _Float16*)dst_tab + (size_t)di * 128;
                #pragma unroll
                for (int kk = 0; kk < 4; ++kk) a0[s][kk]     = *(const half8*)(rs + kk * 32 + g * 8);
                #pragma unroll
                for (int kk = 0; kk < 4; ++kk) a0[s][4 + kk] = *(const half8*)(rd + kk * 32 + g * 8);
            } else {
                const float* rs = (const float*)src_tab + (size_t)si * 128;
                const float* rd = (const float*)dst_tab + (size_t)di * 128;
                #pragma unroll
                for (int kk = 0; kk < 8; ++kk) {
                    const float* base = (kk < 4) ? (rs + kk * 32 + g * 8)
                                                 : (rd + (kk - 4) * 32 + g * 8);
                    float4 p0 = *(const float4*)base;
                    float4 p1 = *(const float4*)(base + 4);
                    half8 fr;
                    fr[0] = (_Float16)p0.x; fr[1] = (_Float16)p0.y;
                    fr[2] = (_Float16)p0.z; fr[3] = (_Float16)p0.w;
                    fr[4] = (_Float16)p1.x; fr[5] = (_Float16)p1.y;
                    fr[6] = (_Float16)p1.z; fr[7] = (_Float16)p1.w;
                    a0[s][kk] = fr;
                }
            }
        }

        // ---- layer 0: H0[32x128] = X @ W0 ----
        f32x4 acc[2][8];
        #pragma unroll
        for (int s = 0; s < 2; ++s)
            #pragma unroll
            for (int j = 0; j < 8; ++j) acc[s][j] = (f32x4){0.f, 0.f, 0.f, 0.f};
        #pragma unroll
        for (int kk = 0; kk < 8; ++kk) {
            #pragma unroll
            for (int j = 0; j < 8; ++j) {
                half8 bf = w0f[(kk * 8 + j) * 64 + l];
                acc[0][j] = __builtin_amdgcn_mfma_f32_16x16x32_f16(a0[0][kk], bf, acc[0][j], 0, 0, 0);
                acc[1][j] = __builtin_amdgcn_mfma_f32_16x16x32_f16(a0[1][kk], bf, acc[1][j], 0, 0, 0);
            }
        }

        // ---- bias+ELU, transpose C-layout -> A-layout via wave-private LDS ----
        half8 a1[2][4];
        #pragma unroll
        for (int s = 0; s < 2; ++s) {
            #pragma unroll
            for (int j = 0; j < 8; ++j) {
                const int kk2 = j >> 1;
                const int g2 = ((j & 1) << 1) | (n >> 3);
                const int jp = n & 7;
                #pragma unroll
                for (int v = 0; v < 4; ++v) {
                    float h = acc[s][j][v] + b0r[j];        // C: row=g*4+v, col=j*16+n
                    h = (h > 0.f) ? h : (__expf(h) - 1.f);  // ELU
                    tbuf[kk2 * 512 + (g * 4 + v + 16 * g2) * 8 + jp] = (_Float16)h;
                }
            }
            __asm__ __volatile__("s_waitcnt lgkmcnt(0)" ::: "memory");
            #pragma unroll
            for (int kk2 = 0; kk2 < 4; ++kk2)
                a1[s][kk2] = *(const half8*)&tbuf[kk2 * 512 + l * 8];
            __asm__ __volatile__("s_waitcnt lgkmcnt(0)" ::: "memory"); // reads done before set1 overwrites
        }

        // ---- layer 1: H1[32x128] = H0 @ W1 ----
        f32x4 acc1[2][8];
        #pragma unroll
        for (int s = 0; s < 2; ++s)
            #pragma unroll
            for (int j = 0; j < 8; ++j) acc1[s][j] = (f32x4){0.f, 0.f, 0.f, 0.f};
        #pragma unroll
        for (int kk = 0; kk < 4; ++kk) {
            #pragma unroll
            for (int j = 0; j < 8; ++j) {
                half8 bf = w1f[(kk * 8 + j) * 64 + l];
                acc1[0][j] = __builtin_amdgcn_mfma_f32_16x16x32_f16(a1[0][kk], bf, acc1[0][j], 0, 0, 0);
                acc1[1][j] = __builtin_amdgcn_mfma_f32_16x16x32_f16(a1[1][kk], bf, acc1[1][j], 0, 0, 0);
            }
        }

        // ---- layer 2 (128->1) on VALU + lane reduce + sigmoid + store ----
        #pragma unroll
        for (int s = 0; s < 2; ++s) {
            float p0 = 0.f, p1 = 0.f, p2 = 0.f, p3 = 0.f;
            #pragma unroll
            for (int j = 0; j < 8; ++j) {
                float h;
                h = acc1[s][j][0] + b1r[j]; h = (h > 0.f) ? h : (__expf(h) - 1.f); p0 += h * w2r[j];
                h = acc1[s][j][1] + b1r[j]; h = (h > 0.f) ? h : (__expf(h) - 1.f); p1 += h * w2r[j];
                h = acc1[s][j][2] + b1r[j]; h = (h > 0.f) ? h : (__expf(h) - 1.f); p2 += h * w2r[j];
                h = acc1[s][j][3] + b1r[j]; h = (h > 0.f) ? h : (__expf(h) - 1.f); p3 += h * w2r[j];
            }
            #pragma unroll
            for (int mask = 1; mask < 16; mask <<= 1) {
                p0 += __shfl_xor(p0, mask);
                p1 += __shfl_xor(p1, mask);
                p2 += __shfl_xor(p2, mask);
                p3 += __shfl_xor(p3, mask);
            }
            if (n == 0) {   // lanes 0,16,32,48 each hold rows g*4 .. g*4+3
                float4 o;
                o.x = 1.f / (1.f + __expf(-(p0 + b2s)));
                o.y = 1.f / (1.f + __expf(-(p1 + b2s)));
                o.z = 1.f / (1.f + __expf(-(p2 + b2s)));
                o.w = 1.f / (1.f + __expf(-(p3 + b2s)));
                *(float4*)&out[e0 + s * 16 + g * 4] = o;
            }
        }
    }
}

extern "C" void kernel_launch(void* const* d_in, const int* in_sizes, int n_in,
                              void* d_out, int out_size, void* d_ws, size_t ws_size,
                              hipStream_t stream) {
    const float* user_emb = (const float*)d_in[0];
    const float* item_emb = (const float*)d_in[1];
    const int* ui_src = (const int*)d_in[2];
    const int* ui_dst = (const int*)d_in[3];
    const int* iu_src = (const int*)d_in[4];
    const int* iu_dst = (const int*)d_in[5];
    const float* W0_ui = (const float*)d_in[6];
    const float* b0_ui = (const float*)d_in[7];
    const float* W1_ui = (const float*)d_in[8];
    const float* b1_ui = (const float*)d_in[9];
    const float* W2_ui = (const float*)d_in[10];
    const float* b2_ui = (const float*)d_in[11];
    const float* W0_iu = (const float*)d_in[12];
    const float* b0_iu = (const float*)d_in[13];
    const float* W1_iu = (const float*)d_in[14];
    const float* b1_iu = (const float*)d_in[15];
    const float* W2_iu = (const float*)d_in[16];
    const float* b2_iu = (const float*)d_in[17];
    float* out = (float*)d_out;

    const size_t nuser = (size_t)100000 * 128;
    const size_t nitem = (size_t)50000 * 128;
    const size_t need = (nuser + nitem) * sizeof(unsigned short);

    if (ws_size >= need) {
        _Float16* u16 = (_Float16*)d_ws;
        _Float16* i16 = u16 + nuser;
        cvt_f32_f16<<<dim3((unsigned)(nuser / 1024)), dim3(256), 0, stream>>>(user_emb, u16, (int)(nuser / 4));
        cvt_f32_f16<<<dim3((unsigned)(nitem / 1024)), dim3(256), 0, stream>>>(item_emb, i16, (int)(nitem / 4));
        edge_mlp<true><<<dim3(256), dim3(512), 0, stream>>>(
            (const void*)u16, (const void*)i16, ui_src, ui_dst,
            W0_ui, b0_ui, W1_ui, b1_ui, W2_ui, b2_ui, out);
        edge_mlp<true><<<dim3(256), dim3(512), 0, stream>>>(
            (const void*)i16, (const void*)u16, iu_src, iu_dst,
            W0_iu, b0_iu, W1_iu, b1_iu, W2_iu, b2_iu, out + E_EDGES);
    } else {
        edge_mlp<false><<<dim3(256), dim3(512), 0, stream>>>(
            (const void*)user_emb, (const void*)item_emb, ui_src, ui_dst,
            W0_ui, b0_ui, W1_ui, b1_ui, W2_ui, b2_ui, out);
        edge_mlp<false><<<dim3(256), dim3(512), 0, stream>>>(
            (const void*)item_emb, (const void*)user_emb, iu_src, iu_dst,
            W0_iu, b0_iu, W1_iu, b1_iu, W2_iu, b2_iu, out + E_EDGES);
    }
}